// Round 12
// baseline (204.869 us; speedup 1.0000x reference)
//
#include <hip/hip_runtime.h>

typedef float  f4    __attribute__((ext_vector_type(4)));
typedef float  f32x4 __attribute__((ext_vector_type(4)));
typedef short  s16x8 __attribute__((ext_vector_type(8)));
typedef unsigned int u32x4 __attribute__((ext_vector_type(4)));

#define L_SEQ 2048
#define D4    16
#define NC4   512
#define RAD   128
#define NBH   48

#define ZROWS 16
#define NZBLK (NBH * (L_SEQ / ZROWS))   // 6144 Z-role blocks
#define TI    64                        // B-role rows per block
#define NTIL  (L_SEQ / TI)              // 32
#define NBBLK (NBH * NTIL)              // 1536 B-role blocks
#define KROWS (TI + 2*RAD)              // 320 staged K rows
#define NBLK  (NZBLK + NBBLK)           // 7680 = 960 groups of 8

// Role-mixed single kernel: groups of 8 blocks (one per XCD in the dispatch
// round-robin) alternate 4 Z-groups : 1 B-group, so every CU hosts mostly
// pure-streamer Z blocks with MFMA B blocks slotted between -- B's staging
// reads, MFMAs and band stores hide under the continuous Z store stream.
//   Z-role: zero-fill the chunk complement of its 16-row tile's window.
//   B-role: R11-proven MFMA band kernel (bf16 K staged in LDS, 2x
//           mfma_f32_16x16x32_bf16 per 16x16 col-tile, band-masked stores).
// Coverage contract (R10-validated): window of 16-aligned tile ibt =
// [max(0,ibt-128), min(2048,ibt+144)); B writes it, Z writes the complement.

__device__ __forceinline__ unsigned bf16rne(float f) {
    unsigned u = __float_as_uint(f);
    return (u + 0x7FFFu + ((u >> 16) & 1u)) >> 16;   // round-to-nearest-even
}

__global__ __launch_bounds__(256, 4)
void band_mix(const float* __restrict__ Qg, const float* __restrict__ Kg,
              float* __restrict__ outg)
{
    // K rows as 8 16B-units (8 bf16, d-ascending); slot = si*8 + (u ^ (si&7))
    __shared__ u32x4 sK[KROWS * 8];     // 40960 B -> 4 blocks/CU (all roles)

    const int t     = threadIdx.x;
    const int bid   = blockIdx.x;
    const int gid   = bid >> 3;
    const int lane8 = bid & 7;
    const int q5    = gid / 5;
    const int r5    = gid - q5 * 5;

    if (r5 != 4) {
        // ================= Z-role: streaming zero-fill =================
        const int z  = (gid - q5) * 8 + lane8;      // [0, 6144)
        const int bh = z >> 7;
        const int r0 = (z & 127) * ZROWS;           // 16-aligned row-tile base
        f4* __restrict__ O4 = reinterpret_cast<f4*>(outg) + (size_t)bh * L_SEQ * NC4;

        const int wlo = (r0 > RAD ? r0 - RAD : 0) >> 2;
        const int whe = r0 + 144;
        const int whi = (whe < L_SEQ ? whe : L_SEQ) >> 2;
        const int wid = whi - wlo;                  // 36..68
        const int nz  = NC4 - wid;                  // 444..476 zero chunks/row

        const int  jA  = t < wlo ? t : t + wid;     // t < nz always
        const int  z2  = t + 256;
        const int  jB  = z2 < wlo ? z2 : z2 + wid;
        const bool doB = z2 < nz;
        const f4 zero4 = {0.f, 0.f, 0.f, 0.f};
#pragma unroll
        for (int r = 0; r < ZROWS; ++r) {
            f4* rowp = O4 + (size_t)(r0 + r) * NC4;
            rowp[jA] = zero4;
            if (doB) rowp[jB] = zero4;
        }
        return;
    }

    // ================= B-role: MFMA band compute =================
    const int b = q5 * 8 + lane8;                   // [0, 1536)
    // bijective XCD swizzle on B-index (lane8 == XCD id)
    const int swz = (b & 7) * (NBBLK / 8) + (b >> 3);
    const int bh  = swz >> 5;
    const int i0  = (swz & (NTIL - 1)) * TI;

    const f4* __restrict__ K4 = reinterpret_cast<const f4*>(Kg) + (size_t)bh * L_SEQ * D4;
    const f4* __restrict__ Q4 = reinterpret_cast<const f4*>(Qg) + (size_t)bh * L_SEQ * D4;
    float* __restrict__ ob    = outg + (size_t)bh * L_SEQ * L_SEQ;

    const int kbase = i0 - RAD;

    // ---- stage K as bf16: 2560 units, 10 per thread
#pragma unroll 2
    for (int itr = 0; itr < 10; ++itr) {
        const int s  = itr * 256 + t;
        const int si = s >> 3, u = s & 7;
        int row = kbase + si;
        row = row < 0 ? 0 : (row > L_SEQ - 1 ? L_SEQ - 1 : row);  // clamp; never read
        const f4 a = K4[(size_t)row * D4 + 2 * u];
        const f4 bb = K4[(size_t)row * D4 + 2 * u + 1];
        u32x4 w;
        w.x = bf16rne(a.x)  | (bf16rne(a.y)  << 16);
        w.y = bf16rne(a.z)  | (bf16rne(a.w)  << 16);
        w.z = bf16rne(bb.x) | (bf16rne(bb.y) << 16);
        w.w = bf16rne(bb.z) | (bf16rne(bb.w) << 16);
        sK[si * 8 + (u ^ (si & 7))] = w;
    }
    __syncthreads();

    // ---- MFMA: wave wv owns 16-row tile ib = i0 + 16*wv
    {
        const int wv = t >> 6, l = t & 63;
        const int ib = i0 + 16 * wv;
        const int m  = l & 15, g = l >> 4;

        s16x8 A1, A2;
        {
            const size_t qb = (size_t)(ib + m) * D4;
            const f4 qa = Q4[qb + 2 * g];
            const f4 qv = Q4[qb + 2 * g + 1];
            const f4 qc = Q4[qb + 8 + 2 * g];
            const f4 qd = Q4[qb + 8 + 2 * g + 1];
            u32x4 wa, wb;
            wa.x = bf16rne(qa.x) | (bf16rne(qa.y) << 16);
            wa.y = bf16rne(qa.z) | (bf16rne(qa.w) << 16);
            wa.z = bf16rne(qv.x) | (bf16rne(qv.y) << 16);
            wa.w = bf16rne(qv.z) | (bf16rne(qv.w) << 16);
            wb.x = bf16rne(qc.x) | (bf16rne(qc.y) << 16);
            wb.y = bf16rne(qc.z) | (bf16rne(qc.w) << 16);
            wb.z = bf16rne(qd.x) | (bf16rne(qd.y) << 16);
            wb.w = bf16rne(qd.z) | (bf16rne(qd.w) << 16);
            A1 = __builtin_bit_cast(s16x8, wa);
            A2 = __builtin_bit_cast(s16x8, wb);
        }

        const int c_lo  = (ib < RAD) ? ((RAD - ib) >> 4) : 0;
        const int c_hi0 = (2176 - ib) >> 4;
        const int c_hi  = c_hi0 < 17 ? c_hi0 : 17;
        for (int c = c_lo; c < c_hi; ++c) {
            const int si = 16 * (wv + c) + m;
            const u32x4 b1 = sK[si * 8 + ((g    ) ^ (si & 7))];
            const u32x4 b2 = sK[si * 8 + ((4 + g) ^ (si & 7))];
            f32x4 acc = {0.f, 0.f, 0.f, 0.f};
            acc = __builtin_amdgcn_mfma_f32_16x16x32_bf16(A1, __builtin_bit_cast(s16x8, b1), acc, 0, 0, 0);
            acc = __builtin_amdgcn_mfma_f32_16x16x32_bf16(A2, __builtin_bit_cast(s16x8, b2), acc, 0, 0, 0);
            const int j = ib - RAD + 16 * c + m;                    // C col = lane&15
#pragma unroll
            for (int r = 0; r < 4; ++r) {
                const int i = ib + 4 * g + r;                       // C row = 4*(lane>>4)+reg
                const float v = ((unsigned)(i - j + RAD) <= 2u * RAD) ? acc[r] : 0.f;
                ob[(size_t)i * L_SEQ + j] = v;
            }
        }
    }
}

extern "C" void kernel_launch(void* const* d_in, const int* in_sizes, int n_in,
                              void* d_out, int out_size, void* d_ws, size_t ws_size,
                              hipStream_t stream) {
    const float* Q = (const float*)d_in[0];
    const float* K = (const float*)d_in[1];
    float* out = (float*)d_out;
    band_mix<<<NBLK, 256, 0, stream>>>(Q, K, out);
}